// Round 1
// baseline (675.854 us; speedup 1.0000x reference)
//
#include <hip/hip_runtime.h>

#define EPS 1e-6f

constexpr int D     = 128;   // head_dim
constexpr int SEQ   = 4096;  // seq_len
constexpr int NBH   = 64;    // bsz*num_heads
constexpr int KSPLIT = 16;
constexpr int CHUNK  = SEQ / KSPLIT;  // 256
constexpr int KB     = 32;            // staged k-rows per iteration
constexpr int QTILE  = 64;            // q rows per block in pass 2

__device__ __forceinline__ float phi(float x) {
    // elu(x)+1 == x+1 (x>0), exp(x) (x<=0)
    return x > 0.0f ? x + 1.0f : __expf(x);
}

// ---------------- Pass 1: KV[bh][d][e] = sum_k phi(K)[k][d] * V[k][e]; Z[bh][d] = sum_k phi(K)[k][d]
__global__ __launch_bounds__(256) void kv_reduce_kernel(const float* __restrict__ K,
                                                        const float* __restrict__ V,
                                                        float* __restrict__ KV,
                                                        float* __restrict__ Z) {
    __shared__ float sK[KB][D];   // 16 KB (phi applied)
    __shared__ float sV[KB][D];   // 16 KB
    __shared__ float zp[8][D];    // 4 KB

    const int bh    = blockIdx.x;   // 0..63
    const int split = blockIdx.y;   // 0..KSPLIT-1
    const int tid   = threadIdx.x;
    const int dg    = tid >> 4;     // 0..15 -> d-tile
    const int eg    = tid & 15;     // 0..15 -> e-tile

    const int k0 = split * CHUNK;
    const size_t base = (size_t)bh * SEQ * D;

    float acc[8][8];
#pragma unroll
    for (int i = 0; i < 8; ++i)
#pragma unroll
        for (int j = 0; j < 8; ++j) acc[i][j] = 0.0f;
    float zacc[4] = {0.f, 0.f, 0.f, 0.f};

    const int c4 = tid & 31;   // column quad id 0..31
    const int c  = c4 * 4;     // column 0..124
    const int r0 = tid >> 5;   // 0..7

    for (int t0 = 0; t0 < CHUNK; t0 += KB) {
        // stage KB rows of K (with phi) and V, coalesced float4
#pragma unroll
        for (int j = 0; j < KB / 8; ++j) {
            const int r = r0 + 8 * j;
            const size_t goff = base + (size_t)(k0 + t0 + r) * D + c;
            float4 kf = *(const float4*)(K + goff);
            float4 kp;
            kp.x = phi(kf.x); kp.y = phi(kf.y); kp.z = phi(kf.z); kp.w = phi(kf.w);
            *(float4*)(&sK[r][c]) = kp;
            zacc[0] += kp.x; zacc[1] += kp.y; zacc[2] += kp.z; zacc[3] += kp.w;
            float4 vf = *(const float4*)(V + goff);
            *(float4*)(&sV[r][c]) = vf;
        }
        __syncthreads();
#pragma unroll
        for (int kk = 0; kk < KB; ++kk) {
            float a[8], b[8];
            *(float4*)(a)     = *(const float4*)(&sK[kk][dg * 8]);
            *(float4*)(a + 4) = *(const float4*)(&sK[kk][dg * 8 + 4]);
            *(float4*)(b)     = *(const float4*)(&sV[kk][eg * 8]);
            *(float4*)(b + 4) = *(const float4*)(&sV[kk][eg * 8 + 4]);
#pragma unroll
            for (int i = 0; i < 8; ++i)
#pragma unroll
                for (int j = 0; j < 8; ++j)
                    acc[i][j] = fmaf(a[i], b[j], acc[i][j]);
        }
        __syncthreads();
    }

    // accumulate KV into global (8 partial blocks per element -> atomics)
    float* kvb = KV + (size_t)bh * D * D;
#pragma unroll
    for (int i = 0; i < 8; ++i)
#pragma unroll
        for (int j = 0; j < 8; ++j)
            atomicAdd(&kvb[(size_t)(dg * 8 + i) * D + (eg * 8 + j)], acc[i][j]);

    // Z: reduce zacc across the 8 row-groups
#pragma unroll
    for (int i = 0; i < 4; ++i) zp[r0][c + i] = zacc[i];
    __syncthreads();
    if (tid < D) {
        float z = 0.f;
#pragma unroll
        for (int r = 0; r < 8; ++r) z += zp[r][tid];
        atomicAdd(&Z[bh * D + tid], z);
    }
}

// ---------------- Pass 2: out[q][e] = (phi(Q)[q][:] @ KV) / (phi(Q)[q][:] . Z + EPS)
__global__ __launch_bounds__(256) void attn_out_kernel(const float* __restrict__ Q,
                                                       const float* __restrict__ KV,
                                                       const float* __restrict__ Z,
                                                       float* __restrict__ out) {
    __shared__ float sKV[D][D];          // 64 KB
    __shared__ float sQT[D][QTILE + 4];  // transposed phi(Q) tile, padded; ~34 KB
    __shared__ float sZ[D];

    const int bh  = blockIdx.x;
    const int q0  = blockIdx.y * QTILE;
    const int tid = threadIdx.x;
    const int qg  = tid >> 4;   // 0..15
    const int eg  = tid & 15;   // 0..15

    const size_t base = (size_t)bh * SEQ * D;

    // stage KV (4096 float4, 16 per thread)
    {
        const float* src = KV + (size_t)bh * D * D;
#pragma unroll
        for (int j = 0; j < 16; ++j) {
            const int f   = tid + 256 * j;
            const int row = f >> 5;
            const int cc  = (f & 31) * 4;
            *(float4*)(&sKV[row][cc]) = *(const float4*)(src + (size_t)row * D + cc);
        }
        if (tid < D) sZ[tid] = Z[bh * D + tid];
    }
    // stage phi(Q) transposed (64 rows x 128 cols -> sQT[col][row])
    {
#pragma unroll
        for (int j = 0; j < QTILE * D / (256 * 4); ++j) {  // 8
            const int f  = tid + 256 * j;
            const int r  = f >> 5;
            const int cc = (f & 31) * 4;
            float4 qf = *(const float4*)(Q + base + (size_t)(q0 + r) * D + cc);
            sQT[cc + 0][r] = phi(qf.x);
            sQT[cc + 1][r] = phi(qf.y);
            sQT[cc + 2][r] = phi(qf.z);
            sQT[cc + 3][r] = phi(qf.w);
        }
    }
    __syncthreads();

    float acc[4][8];
    float dacc[4] = {0.f, 0.f, 0.f, 0.f};
#pragma unroll
    for (int i = 0; i < 4; ++i)
#pragma unroll
        for (int j = 0; j < 8; ++j) acc[i][j] = 0.0f;

    const int qq = qg * 4;
    const int ee = eg * 8;

#pragma unroll 8
    for (int d = 0; d < D; ++d) {
        float a[4], b[8];
        *(float4*)(a)     = *(const float4*)(&sQT[d][qq]);
        *(float4*)(b)     = *(const float4*)(&sKV[d][ee]);
        *(float4*)(b + 4) = *(const float4*)(&sKV[d][ee + 4]);
        const float zd = sZ[d];
#pragma unroll
        for (int i = 0; i < 4; ++i) dacc[i] = fmaf(a[i], zd, dacc[i]);
#pragma unroll
        for (int i = 0; i < 4; ++i)
#pragma unroll
            for (int j = 0; j < 8; ++j)
                acc[i][j] = fmaf(a[i], b[j], acc[i][j]);
    }

    // epilogue: divide & store
#pragma unroll
    for (int i = 0; i < 4; ++i) {
        const float inv = 1.0f / (dacc[i] + EPS);
        float4 o0, o1;
        o0.x = acc[i][0] * inv; o0.y = acc[i][1] * inv;
        o0.z = acc[i][2] * inv; o0.w = acc[i][3] * inv;
        o1.x = acc[i][4] * inv; o1.y = acc[i][5] * inv;
        o1.z = acc[i][6] * inv; o1.w = acc[i][7] * inv;
        float* dst = out + base + (size_t)(q0 + qq + i) * D + ee;
        *(float4*)(dst)     = o0;
        *(float4*)(dst + 4) = o1;
    }
}

extern "C" void kernel_launch(void* const* d_in, const int* in_sizes, int n_in,
                              void* d_out, int out_size, void* d_ws, size_t ws_size,
                              hipStream_t stream) {
    const float* Q = (const float*)d_in[0];
    const float* K = (const float*)d_in[1];
    const float* V = (const float*)d_in[2];
    float* out = (float*)d_out;

    float* KV = (float*)d_ws;                       // 64*128*128 floats = 4 MB
    float* Z  = KV + (size_t)NBH * D * D;           // 64*128 floats

    const size_t zero_bytes = ((size_t)NBH * D * D + (size_t)NBH * D) * sizeof(float);
    hipMemsetAsync(d_ws, 0, zero_bytes, stream);

    kv_reduce_kernel<<<dim3(NBH, KSPLIT), 256, 0, stream>>>(K, V, KV, Z);
    attn_out_kernel<<<dim3(NBH, SEQ / QTILE), 256, 0, stream>>>(Q, KV, Z, out);
}

// Round 2
// 428.192 us; speedup vs baseline: 1.5784x; 1.5784x over previous
//
#include <hip/hip_runtime.h>

#define EPS 1e-6f

constexpr int D      = 128;   // head_dim
constexpr int SEQ    = 4096;  // seq_len
constexpr int NBH    = 64;    // bsz*num_heads
constexpr int KSPLIT = 16;
constexpr int CHUNK  = SEQ / KSPLIT;  // 256
constexpr int KB     = 32;            // staged k-rows per iteration
constexpr int QTILE  = 32;            // q rows per block in pass 2

__device__ __forceinline__ float phi1(float x) {
    // elu(x)+1 : x>0 -> x+1 ; x<=0 -> exp(x). Branchless.
    return fmaxf(x, 0.0f) + __expf(fminf(x, 0.0f));
}

// ---------------- Pass 1: KV[bh][d][e] = sum_k phi(K)[k][d] * V[k][e]; Z[bh][d] = sum_k phi(K)[k][d]
__global__ __launch_bounds__(256, 2) void kv_reduce_kernel(const float* __restrict__ K,
                                                           const float* __restrict__ V,
                                                           float* __restrict__ KV,
                                                           float* __restrict__ Z) {
    __shared__ float sK[KB][D];   // 16 KB (phi applied)
    __shared__ float sV[KB][D];   // 16 KB
    __shared__ float zp[8][D];    // 4 KB

    const int bh    = blockIdx.x;   // 0..63
    const int split = blockIdx.y;   // 0..KSPLIT-1
    const int tid   = threadIdx.x;
    const int dg    = tid >> 4;     // 0..15 -> owns d rows dg*8..dg*8+7
    const int eg    = tid & 15;     // 0..15 -> owns e cols {eg*4..+3} and {64+eg*4..+3}

    const int k0 = split * CHUNK;
    const size_t base = (size_t)bh * SEQ * D;

    float4 acc[8][2];
#pragma unroll
    for (int i = 0; i < 8; ++i) {
        acc[i][0] = make_float4(0.f, 0.f, 0.f, 0.f);
        acc[i][1] = make_float4(0.f, 0.f, 0.f, 0.f);
    }
    float zacc0 = 0.f, zacc1 = 0.f, zacc2 = 0.f, zacc3 = 0.f;

    const int c  = (tid & 31) * 4;  // staging column 0..124
    const int r0 = tid >> 5;        // staging row group 0..7

    for (int t0 = 0; t0 < CHUNK; t0 += KB) {
#pragma unroll
        for (int j = 0; j < KB / 8; ++j) {
            const int r = r0 + 8 * j;
            const size_t g = base + (size_t)(k0 + t0 + r) * D + c;
            const float4 kf = *(const float4*)(K + g);
            float4 kp;
            kp.x = phi1(kf.x); kp.y = phi1(kf.y); kp.z = phi1(kf.z); kp.w = phi1(kf.w);
            *(float4*)(&sK[r][c]) = kp;
            zacc0 += kp.x; zacc1 += kp.y; zacc2 += kp.z; zacc3 += kp.w;
            *(float4*)(&sV[r][c]) = *(const float4*)(V + g);
        }
        __syncthreads();
#pragma unroll 8
        for (int kk = 0; kk < KB; ++kk) {
            const float4 a0 = *(const float4*)(&sK[kk][dg * 8]);
            const float4 a1 = *(const float4*)(&sK[kk][dg * 8 + 4]);
            const float4 b0 = *(const float4*)(&sV[kk][eg * 4]);
            const float4 b1 = *(const float4*)(&sV[kk][64 + eg * 4]);
#define P1_ROW(I, AV)                                          \
            acc[I][0].x = fmaf(AV, b0.x, acc[I][0].x);         \
            acc[I][0].y = fmaf(AV, b0.y, acc[I][0].y);         \
            acc[I][0].z = fmaf(AV, b0.z, acc[I][0].z);         \
            acc[I][0].w = fmaf(AV, b0.w, acc[I][0].w);         \
            acc[I][1].x = fmaf(AV, b1.x, acc[I][1].x);         \
            acc[I][1].y = fmaf(AV, b1.y, acc[I][1].y);         \
            acc[I][1].z = fmaf(AV, b1.z, acc[I][1].z);         \
            acc[I][1].w = fmaf(AV, b1.w, acc[I][1].w);
            P1_ROW(0, a0.x) P1_ROW(1, a0.y) P1_ROW(2, a0.z) P1_ROW(3, a0.w)
            P1_ROW(4, a1.x) P1_ROW(5, a1.y) P1_ROW(6, a1.z) P1_ROW(7, a1.w)
#undef P1_ROW
        }
        __syncthreads();
    }

    // accumulate KV into global (KSPLIT partial blocks per element -> atomics)
    float* kvb = KV + (size_t)bh * D * D;
#pragma unroll
    for (int i = 0; i < 8; ++i) {
        float* p0 = kvb + (size_t)(dg * 8 + i) * D + eg * 4;
        atomicAdd(p0 + 0, acc[i][0].x);
        atomicAdd(p0 + 1, acc[i][0].y);
        atomicAdd(p0 + 2, acc[i][0].z);
        atomicAdd(p0 + 3, acc[i][0].w);
        float* p1 = p0 + 64;
        atomicAdd(p1 + 0, acc[i][1].x);
        atomicAdd(p1 + 1, acc[i][1].y);
        atomicAdd(p1 + 2, acc[i][1].z);
        atomicAdd(p1 + 3, acc[i][1].w);
    }

    // Z: reduce zacc across the 8 row-groups
    zp[r0][c + 0] = zacc0;
    zp[r0][c + 1] = zacc1;
    zp[r0][c + 2] = zacc2;
    zp[r0][c + 3] = zacc3;
    __syncthreads();
    if (tid < D) {
        float z = 0.f;
#pragma unroll
        for (int r = 0; r < 8; ++r) z += zp[r][tid];
        atomicAdd(&Z[bh * D + tid], z);
    }
}

// ---------------- Pass 2: out[q][e] = (phi(Q)[q][:] @ KV) / (phi(Q)[q][:] . Z + EPS)
__global__ __launch_bounds__(256, 2) void attn_out_kernel(const float* __restrict__ Q,
                                                          const float* __restrict__ KV,
                                                          const float* __restrict__ Z,
                                                          float* __restrict__ out) {
    __shared__ float sKV[D][D];       // 64 KB
    __shared__ float sQ[QTILE][D];    // 16 KB, row-rotated by 8*r to break bank conflicts

    const int bh  = blockIdx.x;
    const int q0  = blockIdx.y * QTILE;
    const int tid = threadIdx.x;
    const int qg  = tid >> 4;   // 0..15 -> q rows {2qg, 2qg+1}
    const int eg  = tid & 15;   // 0..15 -> e cols {eg*4..+3} and {64+eg*4..+3}

    const size_t base = (size_t)bh * SEQ * D;

    // stage KV (4096 float4, 16 per thread)
    {
        const float* src = KV + (size_t)bh * D * D;
#pragma unroll
        for (int j = 0; j < 16; ++j) {
            const int f   = tid + 256 * j;
            const int row = f >> 5;
            const int cc  = (f & 31) * 4;
            *(float4*)(&sKV[row][cc]) = *(const float4*)(src + row * D + cc);
        }
    }
    // stage phi(Q), row r rotated by 8r columns (mod 128)
    {
#pragma unroll
        for (int j = 0; j < QTILE * D / (256 * 4); ++j) {  // 4
            const int f  = tid + 256 * j;
            const int r  = f >> 5;
            const int cc = (f & 31) * 4;
            const float4 qf = *(const float4*)(Q + base + (size_t)(q0 + r) * D + cc);
            float4 qp;
            qp.x = phi1(qf.x); qp.y = phi1(qf.y); qp.z = phi1(qf.z); qp.w = phi1(qf.w);
            *(float4*)(&sQ[r][(cc + 8 * r) & 127]) = qp;
        }
    }
    __syncthreads();

    const float* Zr = Z + bh * D;
    float4 acc00 = make_float4(0.f, 0.f, 0.f, 0.f);
    float4 acc01 = make_float4(0.f, 0.f, 0.f, 0.f);
    float4 acc10 = make_float4(0.f, 0.f, 0.f, 0.f);
    float4 acc11 = make_float4(0.f, 0.f, 0.f, 0.f);
    float den0 = 0.f, den1 = 0.f;

    const int qa = 2 * qg, qb = 2 * qg + 1;
    const int rotA = 8 * qa, rotB = 8 * qb;
    const int ee0 = eg * 4, ee1 = 64 + eg * 4;

#pragma unroll 2
    for (int d = 0; d < D; d += 4) {
        const float4 z4  = *(const float4*)(Zr + d);
        const float4 aq0 = *(const float4*)(&sQ[qa][(d + rotA) & 127]);
        const float4 aq1 = *(const float4*)(&sQ[qb][(d + rotB) & 127]);
#define P2_STEP(DD, A0C, A1C, ZC) {                                        \
        const float4 b0 = *(const float4*)(&sKV[d + DD][ee0]);             \
        const float4 b1 = *(const float4*)(&sKV[d + DD][ee1]);             \
        den0 = fmaf(A0C, ZC, den0);                                        \
        den1 = fmaf(A1C, ZC, den1);                                        \
        acc00.x = fmaf(A0C, b0.x, acc00.x); acc00.y = fmaf(A0C, b0.y, acc00.y); \
        acc00.z = fmaf(A0C, b0.z, acc00.z); acc00.w = fmaf(A0C, b0.w, acc00.w); \
        acc01.x = fmaf(A0C, b1.x, acc01.x); acc01.y = fmaf(A0C, b1.y, acc01.y); \
        acc01.z = fmaf(A0C, b1.z, acc01.z); acc01.w = fmaf(A0C, b1.w, acc01.w); \
        acc10.x = fmaf(A1C, b0.x, acc10.x); acc10.y = fmaf(A1C, b0.y, acc10.y); \
        acc10.z = fmaf(A1C, b0.z, acc10.z); acc10.w = fmaf(A1C, b0.w, acc10.w); \
        acc11.x = fmaf(A1C, b1.x, acc11.x); acc11.y = fmaf(A1C, b1.y, acc11.y); \
        acc11.z = fmaf(A1C, b1.z, acc11.z); acc11.w = fmaf(A1C, b1.w, acc11.w); }
        P2_STEP(0, aq0.x, aq1.x, z4.x)
        P2_STEP(1, aq0.y, aq1.y, z4.y)
        P2_STEP(2, aq0.z, aq1.z, z4.z)
        P2_STEP(3, aq0.w, aq1.w, z4.w)
#undef P2_STEP
    }

    const float inv0 = 1.0f / (den0 + EPS);
    const float inv1 = 1.0f / (den1 + EPS);
    float* o0 = out + base + (size_t)(q0 + qa) * D;
    float* o1 = out + base + (size_t)(q0 + qb) * D;
    float4 w;
    w.x = acc00.x * inv0; w.y = acc00.y * inv0; w.z = acc00.z * inv0; w.w = acc00.w * inv0;
    *(float4*)(o0 + ee0) = w;
    w.x = acc01.x * inv0; w.y = acc01.y * inv0; w.z = acc01.z * inv0; w.w = acc01.w * inv0;
    *(float4*)(o0 + ee1) = w;
    w.x = acc10.x * inv1; w.y = acc10.y * inv1; w.z = acc10.z * inv1; w.w = acc10.w * inv1;
    *(float4*)(o1 + ee0) = w;
    w.x = acc11.x * inv1; w.y = acc11.y * inv1; w.z = acc11.z * inv1; w.w = acc11.w * inv1;
    *(float4*)(o1 + ee1) = w;
}

extern "C" void kernel_launch(void* const* d_in, const int* in_sizes, int n_in,
                              void* d_out, int out_size, void* d_ws, size_t ws_size,
                              hipStream_t stream) {
    const float* Q = (const float*)d_in[0];
    const float* K = (const float*)d_in[1];
    const float* V = (const float*)d_in[2];
    float* out = (float*)d_out;

    float* KV = (float*)d_ws;                       // 64*128*128 floats = 4 MB
    float* Z  = KV + (size_t)NBH * D * D;           // 64*128 floats

    const size_t zero_bytes = ((size_t)NBH * D * D + (size_t)NBH * D) * sizeof(float);
    hipMemsetAsync(d_ws, 0, zero_bytes, stream);

    kv_reduce_kernel<<<dim3(NBH, KSPLIT), 256, 0, stream>>>(K, V, KV, Z);
    attn_out_kernel<<<dim3(NBH, SEQ / QTILE), 256, 0, stream>>>(Q, KV, Z, out);
}

// Round 3
// 396.244 us; speedup vs baseline: 1.7057x; 1.0806x over previous
//
#include <hip/hip_runtime.h>

#define EPS 1e-6f

constexpr int D      = 128;   // head_dim
constexpr int SEQ    = 4096;  // seq_len
constexpr int NBH    = 64;    // bsz*num_heads
constexpr int KB     = 32;    // staged k-rows per iteration (pass 1)
constexpr int QTILE  = 32;    // q rows per block (pass 2)
constexpr int DCHUNK = 32;    // KV d-rows staged per chunk (pass 2)

__device__ __forceinline__ float phi1(float x) {
    // elu(x)+1 : x>0 -> x+1 ; x<=0 -> exp(x). Branchless.
    return fmaxf(x, 0.0f) + __expf(fminf(x, 0.0f));
}

// ---------------- Pass 1: partial KV/Z per k-split, plain stores (no atomics)
__global__ __launch_bounds__(256, 4) void kv_partial_kernel(const float* __restrict__ K,
                                                            const float* __restrict__ V,
                                                            float* __restrict__ KVp,
                                                            float* __restrict__ Zp,
                                                            int chunk) {
    __shared__ float sK[KB][D];   // 16 KB (phi applied)
    __shared__ float sV[KB][D];   // 16 KB
    __shared__ float zp[8][D];    // 4 KB  -> 36 KB total, 4 blocks/CU

    const int bh    = blockIdx.x;
    const int split = blockIdx.y;
    const int tid   = threadIdx.x;
    const int dg    = tid >> 4;     // owns d rows dg*8..+7
    const int eg    = tid & 15;     // owns e cols {eg*4..+3} and {64+eg*4..+3}

    const int k0 = split * chunk;
    const size_t base = (size_t)bh * SEQ * D;

    float4 acc[8][2];
#pragma unroll
    for (int i = 0; i < 8; ++i) {
        acc[i][0] = make_float4(0.f, 0.f, 0.f, 0.f);
        acc[i][1] = make_float4(0.f, 0.f, 0.f, 0.f);
    }
    float z0 = 0.f, z1 = 0.f, z2 = 0.f, z3 = 0.f;

    const int c  = (tid & 31) * 4;  // staging column 0..124
    const int r0 = tid >> 5;        // staging row group 0..7

    // prefetch tile 0 into registers
    float4 pk[4], pv[4];
#pragma unroll
    for (int j = 0; j < 4; ++j) {
        const size_t g = base + (size_t)(k0 + r0 + 8 * j) * D + c;
        pk[j] = *(const float4*)(K + g);
        pv[j] = *(const float4*)(V + g);
    }

    for (int t0 = 0; t0 < chunk; t0 += KB) {
        // write staged registers to LDS (phi on K), accumulate Z
#pragma unroll
        for (int j = 0; j < 4; ++j) {
            const int r = r0 + 8 * j;
            float4 kp;
            kp.x = phi1(pk[j].x); kp.y = phi1(pk[j].y);
            kp.z = phi1(pk[j].z); kp.w = phi1(pk[j].w);
            *(float4*)(&sK[r][c]) = kp;
            z0 += kp.x; z1 += kp.y; z2 += kp.z; z3 += kp.w;
            *(float4*)(&sV[r][c]) = pv[j];
        }
        __syncthreads();

        // issue next tile's global loads early — they fly under the FMA loop
        if (t0 + KB < chunk) {
#pragma unroll
            for (int j = 0; j < 4; ++j) {
                const size_t g = base + (size_t)(k0 + t0 + KB + r0 + 8 * j) * D + c;
                pk[j] = *(const float4*)(K + g);
                pv[j] = *(const float4*)(V + g);
            }
        }

#pragma unroll 8
        for (int kk = 0; kk < KB; ++kk) {
            const float4 a0 = *(const float4*)(&sK[kk][dg * 8]);
            const float4 a1 = *(const float4*)(&sK[kk][dg * 8 + 4]);
            const float4 b0 = *(const float4*)(&sV[kk][eg * 4]);
            const float4 b1 = *(const float4*)(&sV[kk][64 + eg * 4]);
#define P1_ROW(I, AV)                                          \
            acc[I][0].x = fmaf(AV, b0.x, acc[I][0].x);         \
            acc[I][0].y = fmaf(AV, b0.y, acc[I][0].y);         \
            acc[I][0].z = fmaf(AV, b0.z, acc[I][0].z);         \
            acc[I][0].w = fmaf(AV, b0.w, acc[I][0].w);         \
            acc[I][1].x = fmaf(AV, b1.x, acc[I][1].x);         \
            acc[I][1].y = fmaf(AV, b1.y, acc[I][1].y);         \
            acc[I][1].z = fmaf(AV, b1.z, acc[I][1].z);         \
            acc[I][1].w = fmaf(AV, b1.w, acc[I][1].w);
            P1_ROW(0, a0.x) P1_ROW(1, a0.y) P1_ROW(2, a0.z) P1_ROW(3, a0.w)
            P1_ROW(4, a1.x) P1_ROW(5, a1.y) P1_ROW(6, a1.z) P1_ROW(7, a1.w)
#undef P1_ROW
        }
        __syncthreads();
    }

    // plain coalesced stores of this split's partial KV
    float* kvb = KVp + ((size_t)split * NBH + bh) * D * D;
#pragma unroll
    for (int i = 0; i < 8; ++i) {
        float* p = kvb + (size_t)(dg * 8 + i) * D + eg * 4;
        *(float4*)(p)      = acc[i][0];
        *(float4*)(p + 64) = acc[i][1];
    }

    // Z partial: reduce across the 8 row-groups, plain store
    zp[r0][c + 0] = z0;
    zp[r0][c + 1] = z1;
    zp[r0][c + 2] = z2;
    zp[r0][c + 3] = z3;
    __syncthreads();
    if (tid < D) {
        float z = 0.f;
#pragma unroll
        for (int r = 0; r < 8; ++r) z += zp[r][tid];
        Zp[((size_t)split * NBH + bh) * D + tid] = z;
    }
}

// ---------------- Reduce partials: KV = sum_s KVp[s], Z = sum_s Zp[s]
__global__ __launch_bounds__(256) void reduce_partials_kernel(const float4* __restrict__ KVp,
                                                              const float4* __restrict__ Zp,
                                                              float4* __restrict__ KV,
                                                              float4* __restrict__ Z,
                                                              int P) {
    constexpr int KVF4 = NBH * D * D / 4;  // 262144
    constexpr int ZF4  = NBH * D / 4;      // 2048
    const int idx = blockIdx.x * 256 + threadIdx.x;
    if (idx < KVF4) {
        float4 a = KVp[idx];
        for (int s = 1; s < P; ++s) {
            const float4 b = KVp[(size_t)s * KVF4 + idx];
            a.x += b.x; a.y += b.y; a.z += b.z; a.w += b.w;
        }
        KV[idx] = a;
    } else if (idx < KVF4 + ZF4) {
        const int zi = idx - KVF4;
        float4 a = Zp[zi];
        for (int s = 1; s < P; ++s) {
            const float4 b = Zp[(size_t)s * ZF4 + zi];
            a.x += b.x; a.y += b.y; a.z += b.z; a.w += b.w;
        }
        Z[zi] = a;
    }
}

// ---------------- Pass 2: out[q][e] = (phi(Q)[q][:] @ KV) / (phi(Q)[q][:] . Z + EPS)
__global__ __launch_bounds__(256, 4) void attn_out_kernel(const float* __restrict__ Q,
                                                          const float* __restrict__ KV,
                                                          const float* __restrict__ Z,
                                                          float* __restrict__ out) {
    __shared__ float sKV[DCHUNK][D];   // 16 KB (chunk of 32 d-rows)
    __shared__ float sQ[QTILE][D];     // 16 KB, row-rotated by 8r
    __shared__ float sZ[D];            // 0.5 KB  -> ~33 KB, 4 blocks/CU

    const int bh  = blockIdx.x;
    const int q0  = blockIdx.y * QTILE;
    const int tid = threadIdx.x;
    const int qg  = tid >> 4;
    const int eg  = tid & 15;

    const size_t base = (size_t)bh * SEQ * D;
    const float* kvb = KV + (size_t)bh * D * D;

    // prefetch KV chunk 0 into registers (4 float4/thread)
    float4 pc[4];
#pragma unroll
    for (int j = 0; j < 4; ++j) {
        const int f = tid + 256 * j;
        pc[j] = *(const float4*)(kvb + (size_t)(f >> 5) * D + (f & 31) * 4);
    }
    // stage phi(Q), row r rotated by 8r columns (mod 128)
#pragma unroll
    for (int j = 0; j < 4; ++j) {
        const int f  = tid + 256 * j;
        const int r  = f >> 5;
        const int cc = (f & 31) * 4;
        const float4 qf = *(const float4*)(Q + base + (size_t)(q0 + r) * D + cc);
        float4 qp;
        qp.x = phi1(qf.x); qp.y = phi1(qf.y); qp.z = phi1(qf.z); qp.w = phi1(qf.w);
        *(float4*)(&sQ[r][(cc + 8 * r) & 127]) = qp;
    }
    if (tid < D) sZ[tid] = Z[bh * D + tid];

    float4 acc00 = make_float4(0.f, 0.f, 0.f, 0.f);
    float4 acc01 = make_float4(0.f, 0.f, 0.f, 0.f);
    float4 acc10 = make_float4(0.f, 0.f, 0.f, 0.f);
    float4 acc11 = make_float4(0.f, 0.f, 0.f, 0.f);
    float den0 = 0.f, den1 = 0.f;

    const int qa = 2 * qg, qb = 2 * qg + 1;
    const int rotA = 8 * qa, rotB = 8 * qb;
    const int ee0 = eg * 4, ee1 = 64 + eg * 4;

    for (int ch = 0; ch < D / DCHUNK; ++ch) {
        __syncthreads();   // previous chunk's readers done (no-op cost at ch=0)
#pragma unroll
        for (int j = 0; j < 4; ++j) {
            const int f = tid + 256 * j;
            *(float4*)(&sKV[f >> 5][(f & 31) * 4]) = pc[j];
        }
        __syncthreads();

        // prefetch next chunk under the FMA loop
        if (ch + 1 < D / DCHUNK) {
#pragma unroll
            for (int j = 0; j < 4; ++j) {
                const int f = tid + 256 * j;
                pc[j] = *(const float4*)(kvb + (size_t)((ch + 1) * DCHUNK + (f >> 5)) * D + (f & 31) * 4);
            }
        }

#pragma unroll 2
        for (int dl = 0; dl < DCHUNK; dl += 4) {
            const int d = ch * DCHUNK + dl;
            const float4 z4  = *(const float4*)(&sZ[d]);
            const float4 aq0 = *(const float4*)(&sQ[qa][(d + rotA) & 127]);
            const float4 aq1 = *(const float4*)(&sQ[qb][(d + rotB) & 127]);
#define P2_STEP(DD, A0C, A1C, ZC) {                                        \
        const float4 b0 = *(const float4*)(&sKV[dl + DD][ee0]);            \
        const float4 b1 = *(const float4*)(&sKV[dl + DD][ee1]);            \
        den0 = fmaf(A0C, ZC, den0);                                        \
        den1 = fmaf(A1C, ZC, den1);                                        \
        acc00.x = fmaf(A0C, b0.x, acc00.x); acc00.y = fmaf(A0C, b0.y, acc00.y); \
        acc00.z = fmaf(A0C, b0.z, acc00.z); acc00.w = fmaf(A0C, b0.w, acc00.w); \
        acc01.x = fmaf(A0C, b1.x, acc01.x); acc01.y = fmaf(A0C, b1.y, acc01.y); \
        acc01.z = fmaf(A0C, b1.z, acc01.z); acc01.w = fmaf(A0C, b1.w, acc01.w); \
        acc10.x = fmaf(A1C, b0.x, acc10.x); acc10.y = fmaf(A1C, b0.y, acc10.y); \
        acc10.z = fmaf(A1C, b0.z, acc10.z); acc10.w = fmaf(A1C, b0.w, acc10.w); \
        acc11.x = fmaf(A1C, b1.x, acc11.x); acc11.y = fmaf(A1C, b1.y, acc11.y); \
        acc11.z = fmaf(A1C, b1.z, acc11.z); acc11.w = fmaf(A1C, b1.w, acc11.w); }
            P2_STEP(0, aq0.x, aq1.x, z4.x)
            P2_STEP(1, aq0.y, aq1.y, z4.y)
            P2_STEP(2, aq0.z, aq1.z, z4.z)
            P2_STEP(3, aq0.w, aq1.w, z4.w)
#undef P2_STEP
        }
    }

    const float inv0 = 1.0f / (den0 + EPS);
    const float inv1 = 1.0f / (den1 + EPS);
    float* o0 = out + base + (size_t)(q0 + qa) * D;
    float* o1 = out + base + (size_t)(q0 + qb) * D;
    float4 w;
    w.x = acc00.x * inv0; w.y = acc00.y * inv0; w.z = acc00.z * inv0; w.w = acc00.w * inv0;
    *(float4*)(o0 + ee0) = w;
    w.x = acc01.x * inv0; w.y = acc01.y * inv0; w.z = acc01.z * inv0; w.w = acc01.w * inv0;
    *(float4*)(o0 + ee1) = w;
    w.x = acc10.x * inv1; w.y = acc10.y * inv1; w.z = acc10.z * inv1; w.w = acc10.w * inv1;
    *(float4*)(o1 + ee0) = w;
    w.x = acc11.x * inv1; w.y = acc11.y * inv1; w.z = acc11.z * inv1; w.w = acc11.w * inv1;
    *(float4*)(o1 + ee1) = w;
}

extern "C" void kernel_launch(void* const* d_in, const int* in_sizes, int n_in,
                              void* d_out, int out_size, void* d_ws, size_t ws_size,
                              hipStream_t stream) {
    const float* Q = (const float*)d_in[0];
    const float* K = (const float*)d_in[1];
    const float* V = (const float*)d_in[2];
    float* out = (float*)d_out;

    // workspace layout: [KVp: P*NBH*D*D][Zp: P*NBH*D][KV: NBH*D*D][Z: NBH*D] floats
    const size_t per_split_f = (size_t)NBH * D * D + (size_t)NBH * D;
    int P = 16;
    while (P > 1 && ((size_t)P + 1) * per_split_f * sizeof(float) > ws_size) P >>= 1;
    const int chunk = SEQ / P;

    float* KVp = (float*)d_ws;
    float* Zp  = KVp + (size_t)P * NBH * D * D;
    float* KVf = Zp + (size_t)P * NBH * D;
    float* Zf  = KVf + (size_t)NBH * D * D;

    kv_partial_kernel<<<dim3(NBH, P), 256, 0, stream>>>(K, V, KVp, Zp, chunk);

    const int red_threads = NBH * D * D / 4 + NBH * D / 4;
    reduce_partials_kernel<<<(red_threads + 255) / 256, 256, 0, stream>>>(
        (const float4*)KVp, (const float4*)Zp, (float4*)KVf, (float4*)Zf, P);

    attn_out_kernel<<<dim3(NBH, SEQ / QTILE), 256, 0, stream>>>(Q, KVf, Zf, out);
}

// Round 4
// 214.955 us; speedup vs baseline: 3.1442x; 1.8434x over previous
//
#include <hip/hip_runtime.h>

#define EPS 1e-6f

constexpr int D   = 128;   // head_dim
constexpr int SEQ = 4096;  // seq_len
constexpr int NBH = 64;    // bsz*num_heads
constexpr int KB  = 32;    // staged k-rows per iteration (pass 1)
constexpr int QT  = 64;    // q rows per block (pass 2)

typedef __attribute__((ext_vector_type(8))) __bf16 bf16x8;
typedef __attribute__((ext_vector_type(4))) __bf16 bf16x4;
typedef __attribute__((ext_vector_type(4))) float  f32x4;

__device__ __forceinline__ float phi1(float x) {
    // elu(x)+1 : x>0 -> x+1 ; x<=0 -> exp(x). Branchless.
    return fmaxf(x, 0.0f) + __expf(fminf(x, 0.0f));
}

// ---------------- Pass 1: partial KV^T per k-split: KVTp[split][bh][e][d] = sum_k V[k][e]*phi(K)[k][d]
//                  Zp[split][bh][d] = sum_k phi(K)[k][d]
__global__ __launch_bounds__(256, 4) void kv_partial_kernel(const float* __restrict__ K,
                                                            const float* __restrict__ V,
                                                            float* __restrict__ KVTp,
                                                            float* __restrict__ Zp,
                                                            int chunk) {
    __shared__ float sK[KB][D];   // 16 KB (phi applied)
    __shared__ float sV[KB][D];   // 16 KB
    __shared__ float zp[8][D];    // 4 KB  -> 36 KB total, 4 blocks/CU

    const int bh    = blockIdx.x;
    const int split = blockIdx.y;
    const int tid   = threadIdx.x;
    const int rg    = tid >> 4;     // owns e rows rg*8..+7 (a-operand from V)
    const int cg    = tid & 15;     // owns d cols {cg*4..+3} and {64+cg*4..+3} (b from phiK)

    const int k0 = split * chunk;
    const size_t base = (size_t)bh * SEQ * D;

    float4 acc[8][2];
#pragma unroll
    for (int i = 0; i < 8; ++i) {
        acc[i][0] = make_float4(0.f, 0.f, 0.f, 0.f);
        acc[i][1] = make_float4(0.f, 0.f, 0.f, 0.f);
    }
    float z0 = 0.f, z1 = 0.f, z2 = 0.f, z3 = 0.f;

    const int c  = (tid & 31) * 4;  // staging column 0..124
    const int r0 = tid >> 5;        // staging row group 0..7

    // prefetch tile 0 into registers
    float4 pk[4], pv[4];
#pragma unroll
    for (int j = 0; j < 4; ++j) {
        const size_t g = base + (size_t)(k0 + r0 + 8 * j) * D + c;
        pk[j] = *(const float4*)(K + g);
        pv[j] = *(const float4*)(V + g);
    }

    for (int t0 = 0; t0 < chunk; t0 += KB) {
#pragma unroll
        for (int j = 0; j < 4; ++j) {
            const int r = r0 + 8 * j;
            float4 kp;
            kp.x = phi1(pk[j].x); kp.y = phi1(pk[j].y);
            kp.z = phi1(pk[j].z); kp.w = phi1(pk[j].w);
            *(float4*)(&sK[r][c]) = kp;
            z0 += kp.x; z1 += kp.y; z2 += kp.z; z3 += kp.w;
            *(float4*)(&sV[r][c]) = pv[j];
        }
        __syncthreads();

        // issue next tile's global loads early — they fly under the FMA loop
        if (t0 + KB < chunk) {
#pragma unroll
            for (int j = 0; j < 4; ++j) {
                const size_t g = base + (size_t)(k0 + t0 + KB + r0 + 8 * j) * D + c;
                pk[j] = *(const float4*)(K + g);
                pv[j] = *(const float4*)(V + g);
            }
        }

#pragma unroll 8
        for (int kk = 0; kk < KB; ++kk) {
            const float4 a0 = *(const float4*)(&sV[kk][rg * 8]);      // e rows
            const float4 a1 = *(const float4*)(&sV[kk][rg * 8 + 4]);
            const float4 b0 = *(const float4*)(&sK[kk][cg * 4]);      // d cols (phi applied)
            const float4 b1 = *(const float4*)(&sK[kk][64 + cg * 4]);
#define P1_ROW(I, AV)                                          \
            acc[I][0].x = fmaf(AV, b0.x, acc[I][0].x);         \
            acc[I][0].y = fmaf(AV, b0.y, acc[I][0].y);         \
            acc[I][0].z = fmaf(AV, b0.z, acc[I][0].z);         \
            acc[I][0].w = fmaf(AV, b0.w, acc[I][0].w);         \
            acc[I][1].x = fmaf(AV, b1.x, acc[I][1].x);         \
            acc[I][1].y = fmaf(AV, b1.y, acc[I][1].y);         \
            acc[I][1].z = fmaf(AV, b1.z, acc[I][1].z);         \
            acc[I][1].w = fmaf(AV, b1.w, acc[I][1].w);
            P1_ROW(0, a0.x) P1_ROW(1, a0.y) P1_ROW(2, a0.z) P1_ROW(3, a0.w)
            P1_ROW(4, a1.x) P1_ROW(5, a1.y) P1_ROW(6, a1.z) P1_ROW(7, a1.w)
#undef P1_ROW
        }
        __syncthreads();
    }

    // plain coalesced stores of this split's partial KV^T  [e][d]
    float* kvb = KVTp + ((size_t)split * NBH + bh) * D * D;
#pragma unroll
    for (int i = 0; i < 8; ++i) {
        float* p = kvb + (size_t)(rg * 8 + i) * D + cg * 4;
        *(float4*)(p)      = acc[i][0];
        *(float4*)(p + 64) = acc[i][1];
    }

    // Z partial: reduce across the 8 row-groups, plain store
    zp[r0][c + 0] = z0;
    zp[r0][c + 1] = z1;
    zp[r0][c + 2] = z2;
    zp[r0][c + 3] = z3;
    __syncthreads();
    if (tid < D) {
        float z = 0.f;
#pragma unroll
        for (int r = 0; r < 8; ++r) z += zp[r][tid];
        Zp[((size_t)split * NBH + bh) * D + tid] = z;
    }
}

// ---------------- Reduce partials -> bf16: KVT[bh][e][d], Zb[bh][d]
__global__ __launch_bounds__(256) void reduce_bf16_kernel(const float* __restrict__ KVTp,
                                                          const float* __restrict__ Zp,
                                                          __bf16* __restrict__ KVT,
                                                          __bf16* __restrict__ Zb,
                                                          int P) {
    constexpr int KVF8 = NBH * D * D / 8;  // 131072
    constexpr int ZF8  = NBH * D / 8;      // 1024
    const int idx = blockIdx.x * 256 + threadIdx.x;
    if (idx < KVF8) {
        const size_t b0 = (size_t)idx * 8;
        float4 s0 = *(const float4*)(KVTp + b0);
        float4 s1 = *(const float4*)(KVTp + b0 + 4);
        for (int s = 1; s < P; ++s) {
            const float* p = KVTp + (size_t)s * NBH * D * D + b0;
            const float4 a = *(const float4*)(p);
            const float4 b = *(const float4*)(p + 4);
            s0.x += a.x; s0.y += a.y; s0.z += a.z; s0.w += a.w;
            s1.x += b.x; s1.y += b.y; s1.z += b.z; s1.w += b.w;
        }
        bf16x8 o;
        o[0] = (__bf16)s0.x; o[1] = (__bf16)s0.y; o[2] = (__bf16)s0.z; o[3] = (__bf16)s0.w;
        o[4] = (__bf16)s1.x; o[5] = (__bf16)s1.y; o[6] = (__bf16)s1.z; o[7] = (__bf16)s1.w;
        *(bf16x8*)(KVT + b0) = o;
    } else if (idx < KVF8 + ZF8) {
        const size_t b0 = (size_t)(idx - KVF8) * 8;
        float4 s0 = *(const float4*)(Zp + b0);
        float4 s1 = *(const float4*)(Zp + b0 + 4);
        for (int s = 1; s < P; ++s) {
            const float* p = Zp + (size_t)s * NBH * D + b0;
            const float4 a = *(const float4*)(p);
            const float4 b = *(const float4*)(p + 4);
            s0.x += a.x; s0.y += a.y; s0.z += a.z; s0.w += a.w;
            s1.x += b.x; s1.y += b.y; s1.z += b.z; s1.w += b.w;
        }
        bf16x8 o;
        o[0] = (__bf16)s0.x; o[1] = (__bf16)s0.y; o[2] = (__bf16)s0.z; o[3] = (__bf16)s0.w;
        o[4] = (__bf16)s1.x; o[5] = (__bf16)s1.y; o[6] = (__bf16)s1.z; o[7] = (__bf16)s1.w;
        *(bf16x8*)(Zb + b0) = o;
    }
}

// ---------------- Pass 2 (MFMA): out[q][e] = (phiQ[q][:] @ KV) / (phiQ[q][:] . Z + EPS)
// A = phiQ (16q x 32d frags), B = KVT rows (d-contiguous), den via Z-broadcast B-frag.
__global__ __launch_bounds__(256, 3) void attn_out_mfma(const float* __restrict__ Q,
                                                        const __bf16* __restrict__ KVT,
                                                        const __bf16* __restrict__ Zb,
                                                        float* __restrict__ out) {
    __shared__ __bf16 sKVT[D][D];   // 32 KB, row-XOR-swizzled
    __shared__ __bf16 sQ[QT][D];    // 16 KB, row-XOR-swizzled
    __shared__ __bf16 sZ[D];        // 256 B, linear

    const int bh  = blockIdx.x;
    const int q0  = blockIdx.y * QT;
    const int tid = threadIdx.x;
    const int lane = tid & 63;
    const int wave = tid >> 6;
    const size_t base = (size_t)bh * SEQ * D;

    // stage KVT (bf16 global, 16B per thread-op, swizzle: elem-seg ^ (row&7))
    {
        const __bf16* kvg = KVT + (size_t)bh * D * D;
#pragma unroll
        for (int j = 0; j < 8; ++j) {
            const int f   = tid + 256 * j;   // 0..2047 ushort8-chunks
            const int e   = f >> 4;
            const int seg = f & 15;
            const bf16x8 v = *(const bf16x8*)(kvg + (size_t)f * 8);
            *(bf16x8*)(&sKVT[e][(seg ^ (e & 7)) * 8]) = v;
        }
    }
    if (tid < 16) {
        *(bf16x8*)(&sZ[tid * 8]) = *(const bf16x8*)(Zb + bh * D + tid * 8);
    }
    // stage phi(Q) as bf16, swizzled
    {
#pragma unroll
        for (int j = 0; j < 8; ++j) {
            const int f  = tid + 256 * j;    // 2048 float4 = QT*D/4
            const int r  = f >> 5;
            const int c4 = (f & 31) * 4;
            const float4 qv = *(const float4*)(Q + base + (size_t)(q0 + r) * D + c4);
            bf16x4 qb;
            qb[0] = (__bf16)phi1(qv.x); qb[1] = (__bf16)phi1(qv.y);
            qb[2] = (__bf16)phi1(qv.z); qb[3] = (__bf16)phi1(qv.w);
            *(bf16x4*)(&sQ[r][c4 ^ ((r & 7) * 8)]) = qb;
        }
    }
    __syncthreads();

    f32x4 acc[8];
#pragma unroll
    for (int et = 0; et < 8; ++et) acc[et] = (f32x4){0.f, 0.f, 0.f, 0.f};
    f32x4 accz = (f32x4){0.f, 0.f, 0.f, 0.f};

    const int qw   = wave * 16;
    const int lrow = lane & 15;
    const int lq   = lane >> 4;

#pragma unroll
    for (int dblk = 0; dblk < 4; ++dblk) {
        const int dbase = dblk * 32 + lq * 8;
        const int arow  = qw + lrow;
        const bf16x8 af = *(const bf16x8*)(&sQ[arow][dbase ^ ((arow & 7) * 8)]);
        const bf16x8 zf = *(const bf16x8*)(&sZ[dbase]);
        accz = __builtin_amdgcn_mfma_f32_16x16x32_bf16(af, zf, accz, 0, 0, 0);
#pragma unroll
        for (int et = 0; et < 8; ++et) {
            const int brow = et * 16 + lrow;
            const bf16x8 bfr = *(const bf16x8*)(&sKVT[brow][dbase ^ ((brow & 7) * 8)]);
            acc[et] = __builtin_amdgcn_mfma_f32_16x16x32_bf16(af, bfr, acc[et], 0, 0, 0);
        }
    }

    // epilogue: C/D layout col=lane&15, row=(lane>>4)*4+reg
    float inv[4];
#pragma unroll
    for (int r = 0; r < 4; ++r) inv[r] = 1.0f / (accz[r] + EPS);
    float* ob = out + base + (size_t)(q0 + qw + lq * 4) * D + lrow;
#pragma unroll
    for (int r = 0; r < 4; ++r) {
#pragma unroll
        for (int et = 0; et < 8; ++et) {
            ob[(size_t)r * D + et * 16] = acc[et][r] * inv[r];
        }
    }
}

extern "C" void kernel_launch(void* const* d_in, const int* in_sizes, int n_in,
                              void* d_out, int out_size, void* d_ws, size_t ws_size,
                              hipStream_t stream) {
    const float* Q = (const float*)d_in[0];
    const float* K = (const float*)d_in[1];
    const float* V = (const float*)d_in[2];
    float* out = (float*)d_out;

    // ws layout: [KVTp: P*NBH*D*D f32][Zp: P*NBH*D f32][KVT: NBH*D*D bf16][Zb: NBH*D bf16]
    const size_t per_split_f = (size_t)NBH * D * D + (size_t)NBH * D;
    const size_t bf16_bytes  = ((size_t)NBH * D * D + (size_t)NBH * D) * sizeof(__bf16);
    int P = 16;
    while (P > 1 && (size_t)P * per_split_f * sizeof(float) + bf16_bytes > ws_size) P >>= 1;
    const int chunk = SEQ / P;

    float*  KVTp = (float*)d_ws;
    float*  Zp   = KVTp + (size_t)P * NBH * D * D;
    __bf16* KVT  = (__bf16*)(Zp + (size_t)P * NBH * D);
    __bf16* Zb   = KVT + (size_t)NBH * D * D;

    kv_partial_kernel<<<dim3(NBH, P), 256, 0, stream>>>(K, V, KVTp, Zp, chunk);

    constexpr int RED_ITEMS = NBH * D * D / 8 + NBH * D / 8;
    reduce_bf16_kernel<<<(RED_ITEMS + 255) / 256, 256, 0, stream>>>(KVTp, Zp, KVT, Zb, P);

    attn_out_mfma<<<dim3(NBH, SEQ / QT), 256, 0, stream>>>(Q, KVT, Zb, out);
}

// Round 5
// 153.174 us; speedup vs baseline: 4.4123x; 1.4033x over previous
//
#include <hip/hip_runtime.h>

#define EPS 1e-6f

constexpr int D    = 128;   // head_dim
constexpr int SEQ  = 4096;  // seq_len
constexpr int NBH  = 64;    // bsz*num_heads
constexpr int KB   = 32;    // k rows per LDS tile (pass 1)
constexpr int KSTR = 40;    // padded k-stride (elems) for transposed tiles (80 B = 5x16B)
constexpr int QT   = 64;    // q rows per block (pass 2)

typedef __attribute__((ext_vector_type(8)))  __bf16 bf16x8;
typedef __attribute__((ext_vector_type(4)))  __bf16 bf16x4;
typedef __attribute__((ext_vector_type(4)))  float  f32x4;
typedef __attribute__((ext_vector_type(16))) float  f32x16;

__device__ __forceinline__ float phi1(float x) {
    // elu(x)+1 : x>0 -> x+1 ; x<=0 -> exp(x). Branchless.
    return fmaxf(x, 0.0f) + __expf(fminf(x, 0.0f));
}

// ---------------- Pass 1 (MFMA): KVTp[split][bh][e][d] = sum_k V[k][e]*phiK[k][d] (f32 partials)
// A = V^T (e x k) from sVT[e][k]; B = phiK (k x d) from sKT[d][k]; both k-contiguous via
// transpose-on-stage. 8 waves: 0-3 stage K(+phi,+Z), 4-7 stage V; all compute 32e x 64d strips.
__global__ __launch_bounds__(512, 4) void kv_partial_mfma(const float* __restrict__ K,
                                                          const float* __restrict__ V,
                                                          float* __restrict__ KVTp,
                                                          float* __restrict__ Zp,
                                                          int chunk) {
    __shared__ __bf16 sKT[D * KSTR];   // [d][k], phi applied   (10.2 KB)
    __shared__ __bf16 sVT[D * KSTR];   // [e][k]                (10.2 KB)
    __shared__ float  zp[8][D];        // Z partial per k-quad  (4 KB)

    const int bh = blockIdx.x, split = blockIdx.y;
    const int tid  = threadIdx.x;
    const int lane = tid & 63;
    const int wave = tid >> 6;
    const int k0   = split * chunk;
    const size_t base = (size_t)bh * SEQ * D;

    // staging role
    const int  ts  = tid & 255;
    const int  kq  = ts & 7;          // k-quad: stages k-local rows kq*4 .. kq*4+3
    const int  cs  = (ts >> 3) * 4;   // column base (d for K-waves, e for V-waves)
    const bool isK = (tid < 256);
    const float* __restrict__ src = isK ? K : V;

    f32x16 acc0, acc1;
#pragma unroll
    for (int i = 0; i < 16; ++i) { acc0[i] = 0.f; acc1[i] = 0.f; }
    float4 zacc = make_float4(0.f, 0.f, 0.f, 0.f);

    const int tiles = chunk / KB;

    // preload tile 0 (4 consecutive k rows, 4 columns)
    float4 p0, p1, p2, p3;
    {
        const size_t g = base + (size_t)(k0 + kq * 4) * D + cs;
        p0 = *(const float4*)(src + g);
        p1 = *(const float4*)(src + g + D);
        p2 = *(const float4*)(src + g + 2 * D);
        p3 = *(const float4*)(src + g + 3 * D);
    }

    const int erow = (wave >> 1) * 32 + (lane & 31);   // A-fragment row (e)
    const int drow = (wave & 1) * 64 + (lane & 31);    // B-fragment col (d), tile 0
    const int kh   = (lane >> 5) * 8;                  // k-half within a 16-k step

    for (int tt = 0; tt < tiles; ++tt) {
        __syncthreads();   // previous tile's fragment reads complete
        if (isK) {
#define STAGE_K(i, CMP) { \
            float a0 = phi1(p0.CMP), a1 = phi1(p1.CMP), a2 = phi1(p2.CMP), a3 = phi1(p3.CMP); \
            zacc.CMP += a0 + a1 + a2 + a3; \
            bf16x4 wv; wv[0] = (__bf16)a0; wv[1] = (__bf16)a1; wv[2] = (__bf16)a2; wv[3] = (__bf16)a3; \
            *(bf16x4*)(&sKT[(cs + i) * KSTR + kq * 4]) = wv; }
            STAGE_K(0, x) STAGE_K(1, y) STAGE_K(2, z) STAGE_K(3, w)
#undef STAGE_K
        } else {
#define STAGE_V(i, CMP) { \
            bf16x4 wv; wv[0] = (__bf16)p0.CMP; wv[1] = (__bf16)p1.CMP; \
            wv[2] = (__bf16)p2.CMP; wv[3] = (__bf16)p3.CMP; \
            *(bf16x4*)(&sVT[(cs + i) * KSTR + kq * 4]) = wv; }
            STAGE_V(0, x) STAGE_V(1, y) STAGE_V(2, z) STAGE_V(3, w)
#undef STAGE_V
        }
        __syncthreads();

        // issue next tile's global loads early — consumed after the next barrier
        if (tt + 1 < tiles) {
            const size_t g = base + (size_t)(k0 + (tt + 1) * KB + kq * 4) * D + cs;
            p0 = *(const float4*)(src + g);
            p1 = *(const float4*)(src + g + D);
            p2 = *(const float4*)(src + g + 2 * D);
            p3 = *(const float4*)(src + g + 3 * D);
        }

        // 2 k-steps of 16
#pragma unroll
        for (int ks = 0; ks < KB; ks += 16) {
            const bf16x8 af  = *(const bf16x8*)(&sVT[erow * KSTR + ks + kh]);
            const bf16x8 bf0 = *(const bf16x8*)(&sKT[drow * KSTR + ks + kh]);
            const bf16x8 bf1 = *(const bf16x8*)(&sKT[(drow + 32) * KSTR + ks + kh]);
            acc0 = __builtin_amdgcn_mfma_f32_32x32x16_bf16(af, bf0, acc0, 0, 0, 0);
            acc1 = __builtin_amdgcn_mfma_f32_32x32x16_bf16(af, bf1, acc1, 0, 0, 0);
        }
    }

    // store C partials (f32). C/D: col = lane&31, row = (reg&3) + 8*(reg>>2) + 4*(lane>>5)
    float* kvb = KVTp + ((size_t)split * NBH + bh) * D * D;
    const int ebase = (wave >> 1) * 32 + 4 * (lane >> 5);
    const int dcol  = (wave & 1) * 64 + (lane & 31);
#pragma unroll
    for (int r = 0; r < 16; ++r) {
        const int e = ebase + (r & 3) + 8 * (r >> 2);
        kvb[(size_t)e * D + dcol]      = acc0[r];
        kvb[(size_t)e * D + dcol + 32] = acc1[r];
    }

    // Z partial
    if (isK) { *(float4*)(&zp[kq][cs]) = zacc; }
    __syncthreads();
    if (tid < D) {
        float z = 0.f;
#pragma unroll
        for (int r = 0; r < 8; ++r) z += zp[r][tid];
        Zp[((size_t)split * NBH + bh) * D + tid] = z;
    }
}

// ---------------- Reduce partials -> bf16: KVT[bh][e][d], Zb[bh][d]
__global__ __launch_bounds__(256) void reduce_bf16_kernel(const float* __restrict__ KVTp,
                                                          const float* __restrict__ Zp,
                                                          __bf16* __restrict__ KVT,
                                                          __bf16* __restrict__ Zb,
                                                          int P) {
    constexpr int KVF8 = NBH * D * D / 8;  // 131072
    constexpr int ZF8  = NBH * D / 8;      // 1024
    const int idx = blockIdx.x * 256 + threadIdx.x;
    if (idx < KVF8) {
        const size_t b0 = (size_t)idx * 8;
        float4 s0 = *(const float4*)(KVTp + b0);
        float4 s1 = *(const float4*)(KVTp + b0 + 4);
        for (int s = 1; s < P; ++s) {
            const float* p = KVTp + (size_t)s * NBH * D * D + b0;
            const float4 a = *(const float4*)(p);
            const float4 b = *(const float4*)(p + 4);
            s0.x += a.x; s0.y += a.y; s0.z += a.z; s0.w += a.w;
            s1.x += b.x; s1.y += b.y; s1.z += b.z; s1.w += b.w;
        }
        bf16x8 o;
        o[0] = (__bf16)s0.x; o[1] = (__bf16)s0.y; o[2] = (__bf16)s0.z; o[3] = (__bf16)s0.w;
        o[4] = (__bf16)s1.x; o[5] = (__bf16)s1.y; o[6] = (__bf16)s1.z; o[7] = (__bf16)s1.w;
        *(bf16x8*)(KVT + b0) = o;
    } else if (idx < KVF8 + ZF8) {
        const size_t b0 = (size_t)(idx - KVF8) * 8;
        float4 s0 = *(const float4*)(Zp + b0);
        float4 s1 = *(const float4*)(Zp + b0 + 4);
        for (int s = 1; s < P; ++s) {
            const float* p = Zp + (size_t)s * NBH * D + b0;
            const float4 a = *(const float4*)(p);
            const float4 b = *(const float4*)(p + 4);
            s0.x += a.x; s0.y += a.y; s0.z += a.z; s0.w += a.w;
            s1.x += b.x; s1.y += b.y; s1.z += b.z; s1.w += b.w;
        }
        bf16x8 o;
        o[0] = (__bf16)s0.x; o[1] = (__bf16)s0.y; o[2] = (__bf16)s0.z; o[3] = (__bf16)s0.w;
        o[4] = (__bf16)s1.x; o[5] = (__bf16)s1.y; o[6] = (__bf16)s1.z; o[7] = (__bf16)s1.w;
        *(bf16x8*)(Zb + b0) = o;
    }
}

// ---------------- Pass 2 (MFMA): out[q][e] = (phiQ[q][:] @ KV) / (phiQ[q][:] . Z + EPS)
__global__ __launch_bounds__(256, 3) void attn_out_mfma(const float* __restrict__ Q,
                                                        const __bf16* __restrict__ KVT,
                                                        const __bf16* __restrict__ Zb,
                                                        float* __restrict__ out) {
    __shared__ __bf16 sKVT[D][D];   // 32 KB, row-XOR-swizzled
    __shared__ __bf16 sQ[QT][D];    // 16 KB, row-XOR-swizzled
    __shared__ __bf16 sZ[D];        // 256 B, linear

    const int bh  = blockIdx.x;
    const int q0  = blockIdx.y * QT;
    const int tid = threadIdx.x;
    const int lane = tid & 63;
    const int wave = tid >> 6;
    const size_t base = (size_t)bh * SEQ * D;

    // stage KVT (bf16 global, swizzle: 8-elem seg ^ (row&7))
    {
        const __bf16* kvg = KVT + (size_t)bh * D * D;
#pragma unroll
        for (int j = 0; j < 8; ++j) {
            const int f   = tid + 256 * j;
            const int e   = f >> 4;
            const int seg = f & 15;
            const bf16x8 v = *(const bf16x8*)(kvg + (size_t)f * 8);
            *(bf16x8*)(&sKVT[e][(seg ^ (e & 7)) * 8]) = v;
        }
    }
    if (tid < 16) {
        *(bf16x8*)(&sZ[tid * 8]) = *(const bf16x8*)(Zb + bh * D + tid * 8);
    }
    // stage phi(Q) as bf16, swizzled
    {
#pragma unroll
        for (int j = 0; j < 8; ++j) {
            const int f  = tid + 256 * j;
            const int r  = f >> 5;
            const int c4 = (f & 31) * 4;
            const float4 qv = *(const float4*)(Q + base + (size_t)(q0 + r) * D + c4);
            bf16x4 qb;
            qb[0] = (__bf16)phi1(qv.x); qb[1] = (__bf16)phi1(qv.y);
            qb[2] = (__bf16)phi1(qv.z); qb[3] = (__bf16)phi1(qv.w);
            *(bf16x4*)(&sQ[r][c4 ^ ((r & 7) * 8)]) = qb;
        }
    }
    __syncthreads();

    f32x4 acc[8];
#pragma unroll
    for (int et = 0; et < 8; ++et) acc[et] = (f32x4){0.f, 0.f, 0.f, 0.f};
    f32x4 accz = (f32x4){0.f, 0.f, 0.f, 0.f};

    const int qw   = wave * 16;
    const int lrow = lane & 15;
    const int lq   = lane >> 4;

#pragma unroll
    for (int dblk = 0; dblk < 4; ++dblk) {
        const int dbase = dblk * 32 + lq * 8;
        const int arow  = qw + lrow;
        const bf16x8 af = *(const bf16x8*)(&sQ[arow][dbase ^ ((arow & 7) * 8)]);
        const bf16x8 zf = *(const bf16x8*)(&sZ[dbase]);
        accz = __builtin_amdgcn_mfma_f32_16x16x32_bf16(af, zf, accz, 0, 0, 0);
#pragma unroll
        for (int et = 0; et < 8; ++et) {
            const int brow = et * 16 + lrow;
            const bf16x8 bfr = *(const bf16x8*)(&sKVT[brow][dbase ^ ((brow & 7) * 8)]);
            acc[et] = __builtin_amdgcn_mfma_f32_16x16x32_bf16(af, bfr, acc[et], 0, 0, 0);
        }
    }

    // epilogue: C/D layout col=lane&15, row=(lane>>4)*4+reg
    float inv[4];
#pragma unroll
    for (int r = 0; r < 4; ++r) inv[r] = 1.0f / (accz[r] + EPS);
    float* ob = out + base + (size_t)(q0 + qw + lq * 4) * D + lrow;
#pragma unroll
    for (int r = 0; r < 4; ++r) {
#pragma unroll
        for (int et = 0; et < 8; ++et) {
            ob[(size_t)r * D + et * 16] = acc[et][r] * inv[r];
        }
    }
}

extern "C" void kernel_launch(void* const* d_in, const int* in_sizes, int n_in,
                              void* d_out, int out_size, void* d_ws, size_t ws_size,
                              hipStream_t stream) {
    const float* Q = (const float*)d_in[0];
    const float* K = (const float*)d_in[1];
    const float* V = (const float*)d_in[2];
    float* out = (float*)d_out;

    // ws layout: [KVTp: P*NBH*D*D f32][Zp: P*NBH*D f32][KVT: NBH*D*D bf16][Zb: NBH*D bf16]
    const size_t per_split_f = (size_t)NBH * D * D + (size_t)NBH * D;
    const size_t bf16_bytes  = ((size_t)NBH * D * D + (size_t)NBH * D) * sizeof(__bf16);
    int P = 16;
    while (P > 1 && (size_t)P * per_split_f * sizeof(float) + bf16_bytes > ws_size) P >>= 1;
    const int chunk = SEQ / P;   // multiple of KB=32 for all P in {1,2,4,8,16}

    float*  KVTp = (float*)d_ws;
    float*  Zp   = KVTp + (size_t)P * NBH * D * D;
    __bf16* KVT  = (__bf16*)(Zp + (size_t)P * NBH * D);
    __bf16* Zb   = KVT + (size_t)NBH * D * D;

    kv_partial_mfma<<<dim3(NBH, P), 512, 0, stream>>>(K, V, KVTp, Zp, chunk);

    constexpr int RED_ITEMS = NBH * D * D / 8 + NBH * D / 8;
    reduce_bf16_kernel<<<(RED_ITEMS + 255) / 256, 256, 0, stream>>>(KVTp, Zp, KVT, Zb, P);

    attn_out_mfma<<<dim3(NBH, SEQ / QT), 256, 0, stream>>>(Q, KVT, Zb, out);
}